// Round 1
// baseline (1415.515 us; speedup 1.0000x reference)
//
#include <hip/hip_runtime.h>
#include <hip/hip_bf16.h>

#define NEG_SLOPE 0.2f

__device__ __forceinline__ float lrelu(float x) { return x >= 0.f ? x : NEG_SLOPE * x; }

// ---------------- CSR build ----------------
__global__ void hist_kernel(const int* __restrict__ dst, int* __restrict__ counts, int etot) {
    int i = blockIdx.x * blockDim.x + threadIdx.x;
    if (i < etot) atomicAdd(&counts[dst[i]], 1);
}

__global__ __launch_bounds__(1024) void scan_kernel(const int* __restrict__ counts,
                                                    int* __restrict__ row_ptr,
                                                    int* __restrict__ cursor, int n) {
    __shared__ int sums[1024];
    int t = threadIdx.x;
    int chunk = (n + 1023) >> 10;
    int lo = t * chunk;
    int hi = min(lo + chunk, n);
    int s = 0;
    for (int i = lo; i < hi; ++i) s += counts[i];
    sums[t] = s;
    __syncthreads();
    for (int off = 1; off < 1024; off <<= 1) {
        int v = (t >= off) ? sums[t - off] : 0;
        __syncthreads();
        sums[t] += v;
        __syncthreads();
    }
    int prefix = (t == 0) ? 0 : sums[t - 1];
    for (int i = lo; i < hi; ++i) {
        row_ptr[i] = prefix;
        cursor[i] = prefix;
        prefix += counts[i];
    }
    if (t == 0) row_ptr[n] = sums[1023];
}

__global__ void scatter_kernel(const int* __restrict__ src, const int* __restrict__ dst,
                               int* __restrict__ cursor, int* __restrict__ csr_src, int etot) {
    int i = blockIdx.x * blockDim.x + threadIdx.x;
    if (i < etot) {
        int d = dst[i];
        int p = atomicAdd(&cursor[d], 1);
        csr_src[p] = src[i];
    }
}

// ---------------- Layer 1 GEMM: h1 = x @ W1, plus alpha_src/alpha_dst ----------------
// One wave per row; W1 (256x64 = 64KB) staged in LDS; x row loaded as float4/lane.
__global__ __launch_bounds__(256) void gemm1_kernel(const float* __restrict__ x,
                                                    const float* __restrict__ W1,
                                                    const float* __restrict__ att_s,
                                                    const float* __restrict__ att_d,
                                                    float* __restrict__ h1,
                                                    float* __restrict__ as1,
                                                    float* __restrict__ ad1, int n) {
    __shared__ float w[256 * 64];  // 64 KB exactly
    for (int i = threadIdx.x; i < 256 * 64; i += 256) w[i] = W1[i];
    __syncthreads();
    int lane = threadIdx.x & 63;
    int wid = blockIdx.x * 4 + (threadIdx.x >> 6);
    int nw = gridDim.x * 4;
    float asv = att_s[lane];  // att flattened (8,8) row-major matches lane = h*8+c
    float adv = att_d[lane];
    for (int r = wid; r < n; r += nw) {
        float4 xq = ((const float4*)(x + (size_t)r * 256))[lane];
        float acc = 0.f;
#pragma unroll 8
        for (int k0 = 0; k0 < 256; k0 += 4) {
            int sl = k0 >> 2;
            float x0 = __shfl(xq.x, sl);
            float x1 = __shfl(xq.y, sl);
            float x2 = __shfl(xq.z, sl);
            float x3 = __shfl(xq.w, sl);
            acc = fmaf(x0, w[(k0 + 0) * 64 + lane], acc);
            acc = fmaf(x1, w[(k0 + 1) * 64 + lane], acc);
            acc = fmaf(x2, w[(k0 + 2) * 64 + lane], acc);
            acc = fmaf(x3, w[(k0 + 3) * 64 + lane], acc);
        }
        h1[(size_t)r * 64 + lane] = acc;
        float ps = acc * asv, pd = acc * adv;
#pragma unroll
        for (int off = 1; off < 8; off <<= 1) {  // reduce over c within each head (8-lane groups)
            ps += __shfl_xor(ps, off);
            pd += __shfl_xor(pd, off);
        }
        if ((lane & 7) == 0) {
            as1[r * 8 + (lane >> 3)] = ps;
            ad1[r * 8 + (lane >> 3)] = pd;
        }
    }
}

// ---------------- Layer 1 aggregation (per-dst softmax + weighted sum + bias + ELU) ----------------
// One wave per destination node. Atomic-free: CSR gives this node's in-edges.
__global__ __launch_bounds__(256) void agg1_kernel(const float* __restrict__ h1,
                                                   const float* __restrict__ as1,
                                                   const float* __restrict__ ad1,
                                                   const float* __restrict__ b1,
                                                   const int* __restrict__ row_ptr,
                                                   const int* __restrict__ csr_src,
                                                   float* __restrict__ elu1, int n) {
    int lane = threadIdx.x & 63;
    int node = blockIdx.x * 4 + (threadIdx.x >> 6);
    if (node >= n) return;
    int start = row_ptr[node], end = row_ptr[node + 1];
    float4 d0 = *(const float4*)(ad1 + (size_t)node * 8);
    float4 d4 = *(const float4*)(ad1 + (size_t)node * 8 + 4);
    float adv[8] = {d0.x, d0.y, d0.z, d0.w, d4.x, d4.y, d4.z, d4.w};

    // Phase A: per-head max (lane-parallel over edges)
    float m[8];
#pragma unroll
    for (int h = 0; h < 8; ++h) m[h] = -INFINITY;
    for (int e = start + lane; e < end; e += 64) {
        int s = csr_src[e];
        float4 a0 = *(const float4*)(as1 + (size_t)s * 8);
        float4 a4 = *(const float4*)(as1 + (size_t)s * 8 + 4);
        float av[8] = {a0.x, a0.y, a0.z, a0.w, a4.x, a4.y, a4.z, a4.w};
#pragma unroll
        for (int h = 0; h < 8; ++h) m[h] = fmaxf(m[h], lrelu(av[h] + adv[h]));
    }
#pragma unroll
    for (int off = 1; off < 64; off <<= 1) {
#pragma unroll
        for (int h = 0; h < 8; ++h) m[h] = fmaxf(m[h], __shfl_xor(m[h], off));
    }

    // Phase B: per-head denom
    float den[8] = {0.f, 0.f, 0.f, 0.f, 0.f, 0.f, 0.f, 0.f};
    for (int e = start + lane; e < end; e += 64) {
        int s = csr_src[e];
        float4 a0 = *(const float4*)(as1 + (size_t)s * 8);
        float4 a4 = *(const float4*)(as1 + (size_t)s * 8 + 4);
        float av[8] = {a0.x, a0.y, a0.z, a0.w, a4.x, a4.y, a4.z, a4.w};
#pragma unroll
        for (int h = 0; h < 8; ++h) den[h] += __expf(lrelu(av[h] + adv[h]) - m[h]);
    }
#pragma unroll
    for (int off = 1; off < 64; off <<= 1) {
#pragma unroll
        for (int h = 0; h < 8; ++h) den[h] += __shfl_xor(den[h], off);
    }

    // Phase C: weighted aggregate, lane = output channel (h = lane>>3)
    int hh = lane >> 3;
    float mh = m[hh];
    float idh = 1.f / den[hh];
    float adh = adv[hh];
    float o = 0.f;
    for (int e = start; e < end; ++e) {
        int s = csr_src[e];  // wave-uniform load
        float v = lrelu(as1[(size_t)s * 8 + hh] + adh);
        float wgt = __expf(v - mh) * idh;
        o = fmaf(h1[(size_t)s * 64 + lane], wgt, o);  // coalesced 256B gather
    }
    float outv = o + b1[lane];
    outv = outv > 0.f ? outv : __expf(outv) - 1.f;  // ELU fused
    elu1[(size_t)node * 64 + lane] = outv;
}

// ---------------- Layer 2 GEMM: h2 = elu1 @ W2, plus scalar alphas ----------------
__global__ __launch_bounds__(256) void gemm2_kernel(const float* __restrict__ elu1,
                                                    const float* __restrict__ W2,
                                                    const float* __restrict__ att_s,
                                                    const float* __restrict__ att_d,
                                                    float* __restrict__ h2,
                                                    float* __restrict__ as2,
                                                    float* __restrict__ ad2, int n) {
    __shared__ float w[64 * 40];  // 10 KB
    for (int i = threadIdx.x; i < 64 * 40; i += 256) w[i] = W2[i];
    __syncthreads();
    int lane = threadIdx.x & 63;
    int jc = min(lane, 39);
    float asv = att_s[jc];
    float adv = att_d[jc];
    int wid = blockIdx.x * 4 + (threadIdx.x >> 6);
    int nw = gridDim.x * 4;
    for (int r = wid; r < n; r += nw) {
        float xv = elu1[(size_t)r * 64 + lane];
        float acc = 0.f;
#pragma unroll 8
        for (int k = 0; k < 64; ++k) {
            float xk = __shfl(xv, k);
            acc = fmaf(xk, w[k * 40 + jc], acc);
        }
        bool act = lane < 40;
        if (act) h2[(size_t)r * 40 + lane] = acc;
        float ps = act ? acc * asv : 0.f;
        float pd = act ? acc * adv : 0.f;
#pragma unroll
        for (int off = 1; off < 64; off <<= 1) {
            ps += __shfl_xor(ps, off);
            pd += __shfl_xor(pd, off);
        }
        if (lane == 0) {
            as2[r] = ps;
            ad2[r] = pd;
        }
    }
}

// ---------------- Layer 2 aggregation + bias + log_softmax ----------------
__global__ __launch_bounds__(256) void agg2_kernel(const float* __restrict__ h2,
                                                   const float* __restrict__ as2,
                                                   const float* __restrict__ ad2,
                                                   const float* __restrict__ b2,
                                                   const int* __restrict__ row_ptr,
                                                   const int* __restrict__ csr_src,
                                                   float* __restrict__ out, int n) {
    int lane = threadIdx.x & 63;
    int node = blockIdx.x * 4 + (threadIdx.x >> 6);
    if (node >= n) return;
    int start = row_ptr[node], end = row_ptr[node + 1];
    float adn = ad2[node];

    float m = -INFINITY;
    for (int e = start + lane; e < end; e += 64)
        m = fmaxf(m, lrelu(as2[csr_src[e]] + adn));
#pragma unroll
    for (int off = 1; off < 64; off <<= 1) m = fmaxf(m, __shfl_xor(m, off));

    float den = 0.f;
    for (int e = start + lane; e < end; e += 64)
        den += __expf(lrelu(as2[csr_src[e]] + adn) - m);
#pragma unroll
    for (int off = 1; off < 64; off <<= 1) den += __shfl_xor(den, off);
    float inv = 1.f / den;

    int c = min(lane, 39);
    float o = 0.f;
    for (int e = start; e < end; ++e) {
        int s = csr_src[e];
        float wgt = __expf(lrelu(as2[s] + adn) - m) * inv;
        o = fmaf(h2[(size_t)s * 40 + c], wgt, o);
    }
    float val = o + b2[c];
    // log_softmax over 40 classes (lanes >= 40 masked)
    float vm = (lane < 40) ? val : -INFINITY;
#pragma unroll
    for (int off = 1; off < 64; off <<= 1) vm = fmaxf(vm, __shfl_xor(vm, off));
    float ex = (lane < 40) ? __expf(val - vm) : 0.f;
#pragma unroll
    for (int off = 1; off < 64; off <<= 1) ex += __shfl_xor(ex, off);
    if (lane < 40) out[(size_t)node * 40 + lane] = val - vm - __logf(ex);
}

// ---------------- launch ----------------
extern "C" void kernel_launch(void* const* d_in, const int* in_sizes, int n_in,
                              void* d_out, int out_size, void* d_ws, size_t ws_size,
                              hipStream_t stream) {
    const float* x        = (const float*)d_in[0];
    const float* W1       = (const float*)d_in[1];
    const float* att_src1 = (const float*)d_in[2];
    const float* att_dst1 = (const float*)d_in[3];
    const float* b1       = (const float*)d_in[4];
    const float* W2       = (const float*)d_in[5];
    const float* att_src2 = (const float*)d_in[6];
    const float* att_dst2 = (const float*)d_in[7];
    const float* b2       = (const float*)d_in[8];
    const int*   ei       = (const int*)d_in[9];

    int n    = in_sizes[0] / 256;   // 100000
    int etot = in_sizes[9] / 2;     // 1700000
    const int* srcp = ei;
    const int* dstp = ei + etot;

    char* ws = (char*)d_ws;
    size_t off = 0;
    float* h1   = (float*)(ws + off); off += (size_t)n * 64 * 4;   // reused as h2 later
    float* elu1 = (float*)(ws + off); off += (size_t)n * 64 * 4;
    float* as1  = (float*)(ws + off); off += (size_t)n * 8 * 4;
    float* ad1  = (float*)(ws + off); off += (size_t)n * 8 * 4;
    float* as2  = (float*)(ws + off); off += (size_t)n * 4;
    float* ad2  = (float*)(ws + off); off += (size_t)n * 4;
    int* row_ptr = (int*)(ws + off); off += (size_t)(n + 64) * 4;
    int* counts  = (int*)(ws + off); off += (size_t)n * 4;
    int* cursor  = (int*)(ws + off); off += (size_t)n * 4;
    int* csr_src = (int*)(ws + off); off += (size_t)etot * 4;
    float* h2 = h1;
    float* outp = (float*)d_out;

    // CSR build (graph identical for both layers)
    hipMemsetAsync(counts, 0, (size_t)n * 4, stream);
    int eb = (etot + 255) / 256;
    hist_kernel<<<eb, 256, 0, stream>>>(dstp, counts, etot);
    scan_kernel<<<1, 1024, 0, stream>>>(counts, row_ptr, cursor, n);
    scatter_kernel<<<eb, 256, 0, stream>>>(srcp, dstp, cursor, csr_src, etot);

    int nb4 = (n + 3) / 4;
    gemm1_kernel<<<512, 256, 0, stream>>>(x, W1, att_src1, att_dst1, h1, as1, ad1, n);
    agg1_kernel<<<nb4, 256, 0, stream>>>(h1, as1, ad1, b1, row_ptr, csr_src, elu1, n);
    gemm2_kernel<<<1024, 256, 0, stream>>>(elu1, W2, att_src2, att_dst2, h2, as2, ad2, n);
    agg2_kernel<<<nb4, 256, 0, stream>>>(h2, as2, ad2, b2, row_ptr, csr_src, outp, n);
}

// Round 2
// 1060.028 us; speedup vs baseline: 1.3354x; 1.3354x over previous
//
#include <hip/hip_runtime.h>
#include <hip/hip_bf16.h>

#define NEG_SLOPE 0.2f

__device__ __forceinline__ float lrelu(float x) { return x >= 0.f ? x : NEG_SLOPE * x; }

// ---------------- CSR build ----------------
__global__ void hist_kernel(const int* __restrict__ dst, int* __restrict__ counts, int etot) {
    int i = blockIdx.x * blockDim.x + threadIdx.x;
    if (i < etot) atomicAdd(&counts[dst[i]], 1);
}

__global__ __launch_bounds__(1024) void scan_kernel(const int* __restrict__ counts,
                                                    int* __restrict__ row_ptr,
                                                    int* __restrict__ cursor, int n) {
    __shared__ int sums[1024];
    int t = threadIdx.x;
    int chunk = (n + 1023) >> 10;
    int lo = t * chunk;
    int hi = min(lo + chunk, n);
    int s = 0;
    for (int i = lo; i < hi; ++i) s += counts[i];
    sums[t] = s;
    __syncthreads();
    for (int off = 1; off < 1024; off <<= 1) {
        int v = (t >= off) ? sums[t - off] : 0;
        __syncthreads();
        sums[t] += v;
        __syncthreads();
    }
    int prefix = (t == 0) ? 0 : sums[t - 1];
    for (int i = lo; i < hi; ++i) {
        row_ptr[i] = prefix;
        cursor[i] = prefix;
        prefix += counts[i];
    }
    if (t == 0) row_ptr[n] = sums[1023];
}

__global__ void scatter_kernel(const int* __restrict__ src, const int* __restrict__ dst,
                               int* __restrict__ cursor, int* __restrict__ csr_src, int etot) {
    int i = blockIdx.x * blockDim.x + threadIdx.x;
    if (i < etot) {
        int d = dst[i];
        int p = atomicAdd(&cursor[d], 1);
        csr_src[p] = src[i];
    }
}

// ---------------- Layer 1 GEMM: h1 = x @ W1 (register-tiled fp32) ----------------
// 64x64 tile, BK=16, 4x4 micro-tile/thread: 16 fma per 2 ds_read_b128.
__global__ __launch_bounds__(256) void gemm1_kernel(const float* __restrict__ x,
                                                    const float* __restrict__ W1,
                                                    float* __restrict__ h1, int n) {
    __shared__ float As[16][68];  // padded: stride 68*4=272B (16B mult), store conflicts 2-way (free)
    __shared__ float Bs[16][64];
    int tid = threadIdx.x;
    int r0 = blockIdx.x * 64;
    int arow = tid >> 2, akq = tid & 3;   // A staging: 64 rows x 4 k-quads
    int bk = tid >> 4, bcq = tid & 15;    // B staging: 16 k x 16 col-quads
    int tx = tid & 15, ty = tid >> 4;     // compute: 16 col-groups x 16 row-groups
    float acc[4][4] = {{0.f}};
    for (int k0 = 0; k0 < 256; k0 += 16) {
        float4 av = make_float4(0.f, 0.f, 0.f, 0.f);
        int gr = r0 + arow;
        if (gr < n) av = *(const float4*)(x + (size_t)gr * 256 + k0 + 4 * akq);
        float4 bv = *(const float4*)(W1 + (size_t)(k0 + bk) * 64 + 4 * bcq);
        __syncthreads();  // previous compute done before overwrite
        As[4 * akq + 0][arow] = av.x;
        As[4 * akq + 1][arow] = av.y;
        As[4 * akq + 2][arow] = av.z;
        As[4 * akq + 3][arow] = av.w;
        *(float4*)&Bs[bk][4 * bcq] = bv;
        __syncthreads();
#pragma unroll
        for (int k = 0; k < 16; ++k) {
            float4 a = *(const float4*)&As[k][4 * ty];  // broadcast across 16 lanes
            float4 b = *(const float4*)&Bs[k][4 * tx];
            float ar[4] = {a.x, a.y, a.z, a.w};
            float br[4] = {b.x, b.y, b.z, b.w};
#pragma unroll
            for (int i = 0; i < 4; ++i)
#pragma unroll
                for (int j = 0; j < 4; ++j) acc[i][j] = fmaf(ar[i], br[j], acc[i][j]);
        }
    }
#pragma unroll
    for (int i = 0; i < 4; ++i) {
        int gr = r0 + 4 * ty + i;
        if (gr < n) {
            float4 o = make_float4(acc[i][0], acc[i][1], acc[i][2], acc[i][3]);
            *(float4*)(h1 + (size_t)gr * 64 + 4 * tx) = o;
        }
    }
}

// alpha1: as1/ad1 from h1 (wave per row)
__global__ __launch_bounds__(256) void alpha1_kernel(const float* __restrict__ h1,
                                                     const float* __restrict__ att_s,
                                                     const float* __restrict__ att_d,
                                                     float* __restrict__ as1,
                                                     float* __restrict__ ad1, int n) {
    int lane = threadIdx.x & 63;
    int wid = blockIdx.x * 4 + (threadIdx.x >> 6);
    int nw = gridDim.x * 4;
    float s = att_s[lane], d = att_d[lane];
    for (int r = wid; r < n; r += nw) {
        float h = h1[(size_t)r * 64 + lane];
        float ps = h * s, pd = h * d;
#pragma unroll
        for (int off = 1; off < 8; off <<= 1) {
            ps += __shfl_xor(ps, off);
            pd += __shfl_xor(pd, off);
        }
        if ((lane & 7) == 0) {
            as1[r * 8 + (lane >> 3)] = ps;
            ad1[r * 8 + (lane >> 3)] = pd;
        }
    }
}

// ---------------- Layer 1 aggregation (online softmax + weighted sum + bias + ELU) ----------------
__global__ __launch_bounds__(256) void agg1_kernel(const float* __restrict__ h1,
                                                   const float* __restrict__ as1,
                                                   const float* __restrict__ ad1,
                                                   const float* __restrict__ b1,
                                                   const int* __restrict__ row_ptr,
                                                   const int* __restrict__ csr_src,
                                                   float* __restrict__ elu1, int n) {
    int lane = threadIdx.x & 63;
    int node = blockIdx.x * 4 + (threadIdx.x >> 6);
    if (node >= n) return;
    int start = row_ptr[node], end = row_ptr[node + 1];
    float4 d0 = *(const float4*)(ad1 + (size_t)node * 8);
    float4 d4 = *(const float4*)(ad1 + (size_t)node * 8 + 4);
    float adv[8] = {d0.x, d0.y, d0.z, d0.w, d4.x, d4.y, d4.z, d4.w};

    // single pass: online max + denom (finite init avoids -inf - -inf = nan)
    float m[8], den[8];
#pragma unroll
    for (int h = 0; h < 8; ++h) { m[h] = -1e30f; den[h] = 0.f; }
    for (int e = start + lane; e < end; e += 64) {
        int s = csr_src[e];
        float4 a0 = *(const float4*)(as1 + (size_t)s * 8);
        float4 a4 = *(const float4*)(as1 + (size_t)s * 8 + 4);
        float av[8] = {a0.x, a0.y, a0.z, a0.w, a4.x, a4.y, a4.z, a4.w};
#pragma unroll
        for (int h = 0; h < 8; ++h) {
            float v = lrelu(av[h] + adv[h]);
            float nm = fmaxf(m[h], v);
            den[h] = den[h] * __expf(m[h] - nm) + __expf(v - nm);
            m[h] = nm;
        }
    }
#pragma unroll
    for (int off = 1; off < 64; off <<= 1) {
#pragma unroll
        for (int h = 0; h < 8; ++h) {
            float om = __shfl_xor(m[h], off);
            float od = __shfl_xor(den[h], off);
            float nm = fmaxf(m[h], om);
            den[h] = den[h] * __expf(m[h] - nm) + od * __expf(om - nm);
            m[h] = nm;
        }
    }

    // weighted aggregate, lane = output channel (h = lane>>3)
    int hh = lane >> 3;
    float mh = m[hh];
    float idh = 1.f / den[hh];
    float adh = adv[hh];
    float o = 0.f;
    for (int e = start; e < end; ++e) {
        int s = csr_src[e];  // wave-uniform
        float v = lrelu(as1[(size_t)s * 8 + hh] + adh);
        float wgt = __expf(v - mh) * idh;
        o = fmaf(h1[(size_t)s * 64 + lane], wgt, o);  // coalesced 256B gather
    }
    float outv = o + b1[lane];
    outv = outv > 0.f ? outv : __expf(outv) - 1.f;  // ELU fused
    elu1[(size_t)node * 64 + lane] = outv;
}

// ---------------- Layer 2 GEMM: h2 = elu1 @ W2 (register-tiled, whole-K in LDS) ----------------
// 128x40 tile, K=64, 4x5 micro-tile/thread.
__global__ __launch_bounds__(256) void gemm2_kernel(const float* __restrict__ elu1,
                                                    const float* __restrict__ W2,
                                                    float* __restrict__ h2, int n) {
    __shared__ float As[64][132];  // stride 132*4=528B (16B mult)
    __shared__ float Bs[64][40];
    int tid = threadIdx.x;
    int r0 = blockIdx.x * 128;
    for (int t = tid; t < 640; t += 256) {  // B: 64x40 = 640 float4
        int k = t / 10, cq = t % 10;
        *(float4*)&Bs[k][4 * cq] = *(const float4*)(W2 + (size_t)k * 40 + 4 * cq);
    }
    for (int t = tid; t < 2048; t += 256) {  // A: 128 rows x 16 k-quads
        int row = t >> 4, kq = t & 15;
        int gr = r0 + row;
        float4 av = make_float4(0.f, 0.f, 0.f, 0.f);
        if (gr < n) av = *(const float4*)(elu1 + (size_t)gr * 64 + 4 * kq);
        As[4 * kq + 0][row] = av.x;
        As[4 * kq + 1][row] = av.y;
        As[4 * kq + 2][row] = av.z;
        As[4 * kq + 3][row] = av.w;
    }
    __syncthreads();
    int cx = tid & 7, ry = tid >> 3;  // 8 col-groups(5) x 32 row-groups(4)
    float acc[4][5] = {{0.f}};
#pragma unroll 8
    for (int k = 0; k < 64; ++k) {
        float4 a = *(const float4*)&As[k][4 * ry];
        float ar[4] = {a.x, a.y, a.z, a.w};
        float br[5];
#pragma unroll
        for (int j = 0; j < 5; ++j) br[j] = Bs[k][5 * cx + j];
#pragma unroll
        for (int i = 0; i < 4; ++i)
#pragma unroll
            for (int j = 0; j < 5; ++j) acc[i][j] = fmaf(ar[i], br[j], acc[i][j]);
    }
#pragma unroll
    for (int i = 0; i < 4; ++i) {
        int gr = r0 + 4 * ry + i;
        if (gr < n) {
#pragma unroll
            for (int j = 0; j < 5; ++j) h2[(size_t)gr * 40 + 5 * cx + j] = acc[i][j];
        }
    }
}

// alpha2: scalar per-node dot products (40-wide, line-coalesced)
__global__ void alpha2_kernel(const float* __restrict__ h2, const float* __restrict__ att_s,
                              const float* __restrict__ att_d, float* __restrict__ as2,
                              float* __restrict__ ad2, int n) {
    int i = blockIdx.x * blockDim.x + threadIdx.x;
    if (i >= n) return;
    const float* row = h2 + (size_t)i * 40;
    float s = 0.f, d = 0.f;
#pragma unroll
    for (int c = 0; c < 40; ++c) {
        float v = row[c];
        s = fmaf(v, att_s[c], s);
        d = fmaf(v, att_d[c], d);
    }
    as2[i] = s;
    ad2[i] = d;
}

// ---------------- Layer 2 aggregation + bias + log_softmax ----------------
__global__ __launch_bounds__(256) void agg2_kernel(const float* __restrict__ h2,
                                                   const float* __restrict__ as2,
                                                   const float* __restrict__ ad2,
                                                   const float* __restrict__ b2,
                                                   const int* __restrict__ row_ptr,
                                                   const int* __restrict__ csr_src,
                                                   float* __restrict__ out, int n) {
    int lane = threadIdx.x & 63;
    int node = blockIdx.x * 4 + (threadIdx.x >> 6);
    if (node >= n) return;
    int start = row_ptr[node], end = row_ptr[node + 1];
    float adn = ad2[node];

    float m = -1e30f, den = 0.f;
    for (int e = start + lane; e < end; e += 64) {
        float v = lrelu(as2[csr_src[e]] + adn);
        float nm = fmaxf(m, v);
        den = den * __expf(m - nm) + __expf(v - nm);
        m = nm;
    }
#pragma unroll
    for (int off = 1; off < 64; off <<= 1) {
        float om = __shfl_xor(m, off);
        float od = __shfl_xor(den, off);
        float nm = fmaxf(m, om);
        den = den * __expf(m - nm) + od * __expf(om - nm);
        m = nm;
    }
    float inv = 1.f / den;

    int c = min(lane, 39);
    float o = 0.f;
    for (int e = start; e < end; ++e) {
        int s = csr_src[e];
        float wgt = __expf(lrelu(as2[s] + adn) - m) * inv;
        o = fmaf(h2[(size_t)s * 40 + c], wgt, o);
    }
    float val = o + b2[c];
    float vm = (lane < 40) ? val : -1e30f;
#pragma unroll
    for (int off = 1; off < 64; off <<= 1) vm = fmaxf(vm, __shfl_xor(vm, off));
    float ex = (lane < 40) ? __expf(val - vm) : 0.f;
#pragma unroll
    for (int off = 1; off < 64; off <<= 1) ex += __shfl_xor(ex, off);
    if (lane < 40) out[(size_t)node * 40 + lane] = val - vm - __logf(ex);
}

// ---------------- launch ----------------
extern "C" void kernel_launch(void* const* d_in, const int* in_sizes, int n_in,
                              void* d_out, int out_size, void* d_ws, size_t ws_size,
                              hipStream_t stream) {
    const float* x        = (const float*)d_in[0];
    const float* W1       = (const float*)d_in[1];
    const float* att_src1 = (const float*)d_in[2];
    const float* att_dst1 = (const float*)d_in[3];
    const float* b1       = (const float*)d_in[4];
    const float* W2       = (const float*)d_in[5];
    const float* att_src2 = (const float*)d_in[6];
    const float* att_dst2 = (const float*)d_in[7];
    const float* b2       = (const float*)d_in[8];
    const int*   ei       = (const int*)d_in[9];

    int n    = in_sizes[0] / 256;   // 100000
    int etot = in_sizes[9] / 2;     // 1700000
    const int* srcp = ei;
    const int* dstp = ei + etot;

    char* ws = (char*)d_ws;
    size_t off = 0;
    float* h1   = (float*)(ws + off); off += (size_t)n * 64 * 4;   // reused as h2
    float* elu1 = (float*)(ws + off); off += (size_t)n * 64 * 4;
    float* as1  = (float*)(ws + off); off += (size_t)n * 8 * 4;
    float* ad1  = (float*)(ws + off); off += (size_t)n * 8 * 4;
    float* as2  = (float*)(ws + off); off += (size_t)n * 4;
    float* ad2  = (float*)(ws + off); off += (size_t)n * 4;
    int* row_ptr = (int*)(ws + off); off += (size_t)(n + 64) * 4;
    int* counts  = (int*)(ws + off); off += (size_t)n * 4;
    int* cursor  = (int*)(ws + off); off += (size_t)n * 4;
    int* csr_src = (int*)(ws + off); off += (size_t)etot * 4;
    float* h2 = h1;
    float* outp = (float*)d_out;

    hipMemsetAsync(counts, 0, (size_t)n * 4, stream);
    int eb = (etot + 255) / 256;
    hist_kernel<<<eb, 256, 0, stream>>>(dstp, counts, etot);
    scan_kernel<<<1, 1024, 0, stream>>>(counts, row_ptr, cursor, n);
    scatter_kernel<<<eb, 256, 0, stream>>>(srcp, dstp, cursor, csr_src, etot);

    int nb4 = (n + 3) / 4;
    gemm1_kernel<<<(n + 63) / 64, 256, 0, stream>>>(x, W1, h1, n);
    alpha1_kernel<<<512, 256, 0, stream>>>(h1, att_src1, att_dst1, as1, ad1, n);
    agg1_kernel<<<nb4, 256, 0, stream>>>(h1, as1, ad1, b1, row_ptr, csr_src, elu1, n);
    gemm2_kernel<<<(n + 127) / 128, 256, 0, stream>>>(elu1, W2, h2, n);
    alpha2_kernel<<<(n + 255) / 256, 256, 0, stream>>>(h2, att_src2, att_dst2, as2, ad2, n);
    agg2_kernel<<<nb4, 256, 0, stream>>>(h2, as2, ad2, b2, row_ptr, csr_src, outp, n);
}

// Round 3
// 705.129 us; speedup vs baseline: 2.0075x; 1.5033x over previous
//
#include <hip/hip_runtime.h>
#include <hip/hip_bf16.h>

#define NEG_SLOPE 0.2f

__device__ __forceinline__ float lrelu(float x) { return x >= 0.f ? x : NEG_SLOPE * x; }
__device__ __forceinline__ float rdlane_f(float v, int l) {
    return __int_as_float(__builtin_amdgcn_readlane(__float_as_int(v), l));
}

// ---------------- CSR build ----------------
__global__ void hist_kernel(const int* __restrict__ dst, int* __restrict__ counts, int etot) {
    int i = blockIdx.x * blockDim.x + threadIdx.x;
    if (i < etot) atomicAdd(&counts[dst[i]], 1);
}

// parallel scan: A = per-block sums, B = scan of block sums, C = intra-block scan + write
__global__ __launch_bounds__(256) void scanA_kernel(const int* __restrict__ counts,
                                                    int* __restrict__ bsums, int n) {
    __shared__ int sm[256];
    int i = blockIdx.x * 256 + threadIdx.x;
    sm[threadIdx.x] = (i < n) ? counts[i] : 0;
    __syncthreads();
    for (int off = 128; off > 0; off >>= 1) {
        if (threadIdx.x < off) sm[threadIdx.x] += sm[threadIdx.x + off];
        __syncthreads();
    }
    if (threadIdx.x == 0) bsums[blockIdx.x] = sm[0];
}

__global__ __launch_bounds__(1024) void scanB_kernel(int* __restrict__ bsums, int nb) {
    __shared__ int sm[1024];
    int t = threadIdx.x;
    int v = (t < nb) ? bsums[t] : 0;
    sm[t] = v;
    __syncthreads();
    for (int off = 1; off < 1024; off <<= 1) {
        int u = (t >= off) ? sm[t - off] : 0;
        __syncthreads();
        sm[t] += u;
        __syncthreads();
    }
    if (t < nb) bsums[t] = sm[t] - v;  // exclusive
}

__global__ __launch_bounds__(256) void scanC_kernel(const int* __restrict__ counts,
                                                    const int* __restrict__ bsums,
                                                    int* __restrict__ row_ptr,
                                                    int* __restrict__ cursor, int n, int etot) {
    __shared__ int sm[256];
    int t = threadIdx.x;
    int i = blockIdx.x * 256 + t;
    int v = (i < n) ? counts[i] : 0;
    sm[t] = v;
    __syncthreads();
    for (int off = 1; off < 256; off <<= 1) {
        int u = (t >= off) ? sm[t - off] : 0;
        __syncthreads();
        sm[t] += u;
        __syncthreads();
    }
    if (i < n) {
        int ex = bsums[blockIdx.x] + sm[t] - v;
        row_ptr[i] = ex;
        cursor[i] = ex;
    }
    if (i == 0) row_ptr[n] = etot;
}

__global__ void scatter_kernel(const int* __restrict__ src, const int* __restrict__ dst,
                               int* __restrict__ cursor, int* __restrict__ csr_src, int etot) {
    int i = blockIdx.x * blockDim.x + threadIdx.x;
    if (i < etot) {
        int d = dst[i];
        int p = atomicAdd(&cursor[d], 1);
        csr_src[p] = src[i];
    }
}

// ---------------- Layer 1 GEMM: h1 = x @ W1 (128x64 tile, 8x4 micro) ----------------
__global__ __launch_bounds__(256) void gemm1_kernel(const float* __restrict__ x,
                                                    const float* __restrict__ W1,
                                                    float* __restrict__ h1, int n) {
    __shared__ float As[16][132];  // [k][row], 128 rows + 4 pad
    __shared__ float Bs[16][64];
    int tid = threadIdx.x;
    int r0 = blockIdx.x * 128;
    int arow = tid >> 2, akq = tid & 3;  // A: rows arow, arow+64; k-quad akq
    int bk = tid >> 4, bcq = tid & 15;
    int tx = tid & 15, ty = tid >> 4;  // 16 col-groups(4) x 16 row-groups(8)
    float acc[8][4] = {{0.f}};
    for (int k0 = 0; k0 < 256; k0 += 16) {
        int g0 = r0 + arow, g1 = r0 + arow + 64;
        float4 av0 = make_float4(0.f, 0.f, 0.f, 0.f), av1 = av0;
        if (g0 < n) av0 = *(const float4*)(x + (size_t)g0 * 256 + k0 + 4 * akq);
        if (g1 < n) av1 = *(const float4*)(x + (size_t)g1 * 256 + k0 + 4 * akq);
        float4 bv = *(const float4*)(W1 + (size_t)(k0 + bk) * 64 + 4 * bcq);
        __syncthreads();
        As[4 * akq + 0][arow] = av0.x;
        As[4 * akq + 1][arow] = av0.y;
        As[4 * akq + 2][arow] = av0.z;
        As[4 * akq + 3][arow] = av0.w;
        As[4 * akq + 0][arow + 64] = av1.x;
        As[4 * akq + 1][arow + 64] = av1.y;
        As[4 * akq + 2][arow + 64] = av1.z;
        As[4 * akq + 3][arow + 64] = av1.w;
        *(float4*)&Bs[bk][4 * bcq] = bv;
        __syncthreads();
#pragma unroll
        for (int k = 0; k < 16; ++k) {
            float4 a0 = *(const float4*)&As[k][8 * ty];
            float4 a1 = *(const float4*)&As[k][8 * ty + 4];
            float4 b = *(const float4*)&Bs[k][4 * tx];
            float ar[8] = {a0.x, a0.y, a0.z, a0.w, a1.x, a1.y, a1.z, a1.w};
            float br[4] = {b.x, b.y, b.z, b.w};
#pragma unroll
            for (int i = 0; i < 8; ++i)
#pragma unroll
                for (int j = 0; j < 4; ++j) acc[i][j] = fmaf(ar[i], br[j], acc[i][j]);
        }
    }
#pragma unroll
    for (int i = 0; i < 8; ++i) {
        int gr = r0 + 8 * ty + i;
        if (gr < n) {
            float4 o = make_float4(acc[i][0], acc[i][1], acc[i][2], acc[i][3]);
            *(float4*)(h1 + (size_t)gr * 64 + 4 * tx) = o;
        }
    }
}

// alpha1: as1/ad1 from h1 (wave per row)
__global__ __launch_bounds__(256) void alpha1_kernel(const float* __restrict__ h1,
                                                     const float* __restrict__ att_s,
                                                     const float* __restrict__ att_d,
                                                     float* __restrict__ as1,
                                                     float* __restrict__ ad1, int n) {
    int lane = threadIdx.x & 63;
    int wid = blockIdx.x * 4 + (threadIdx.x >> 6);
    int nw = gridDim.x * 4;
    float s = att_s[lane], d = att_d[lane];
    for (int r = wid; r < n; r += nw) {
        float h = h1[(size_t)r * 64 + lane];
        float ps = h * s, pd = h * d;
#pragma unroll
        for (int off = 1; off < 8; off <<= 1) {
            ps += __shfl_xor(ps, off);
            pd += __shfl_xor(pd, off);
        }
        if ((lane & 7) == 0) {
            as1[r * 8 + (lane >> 3)] = ps;
            ad1[r * 8 + (lane >> 3)] = pd;
        }
    }
}

// ---------------- Layer 1 aggregation ----------------
// Softmax pass: lane = (slot,head) — 8 edges x 8 heads per iteration.
// Aggregate pass: scalar src broadcast (readlane) + ds_bpermute weight + 256B gather.
__global__ __launch_bounds__(256) void agg1_kernel(const float* __restrict__ h1,
                                                   const float* __restrict__ as1,
                                                   const float* __restrict__ ad1,
                                                   const float* __restrict__ b1,
                                                   const int* __restrict__ row_ptr,
                                                   const int* __restrict__ csr_src,
                                                   float* __restrict__ elu1, int n) {
    int lane = threadIdx.x & 63;
    int node = blockIdx.x * 4 + (threadIdx.x >> 6);
    if (node >= n) return;
    int start = row_ptr[node], end = row_ptr[node + 1];
    int slot = lane >> 3, hd = lane & 7;
    float adh = ad1[(size_t)node * 8 + hd];

    // pass 1: online softmax, 8 edges x 8 heads per iter
    float m = -1e30f, den = 0.f;
    for (int e0 = start; e0 < end; e0 += 8) {
        int e = e0 + slot;
        bool valid = e < end;
        int ee = valid ? e : end - 1;
        int s = csr_src[ee];
        float v = lrelu(as1[(size_t)s * 8 + hd] + adh);
        if (!valid) v = -INFINITY;
        float nm = fmaxf(m, v);
        den = den * __expf(m - nm) + __expf(v - nm);
        m = nm;
    }
#pragma unroll
    for (int off = 8; off < 64; off <<= 1) {  // merge across slots only
        float om = __shfl_xor(m, off);
        float od = __shfl_xor(den, off);
        float nm = fmaxf(m, om);
        den = den * __expf(m - nm) + od * __expf(om - nm);
        m = nm;
    }
    float inv = 1.f / den;

    // pass 2: recompute w in (slot,head) layout, aggregate with lane = channel
    int hh = lane >> 3;  // channel layout: lane = head*8 + c
    float o = 0.f;
    for (int e0 = start; e0 < end; e0 += 8) {
        int e = e0 + slot;
        int ee = (e < end) ? e : end - 1;
        int s = csr_src[ee];
        float v = lrelu(as1[(size_t)s * 8 + hd] + adh);
        float w = __expf(v - m) * inv;  // invalid slots: v=-large => w~0, never read anyway
        int nv = min(8, end - e0);
        for (int j = 0; j < nv; ++j) {
            int sj = __builtin_amdgcn_readlane(s, j * 8);  // scalar src row
            float wj = __shfl(w, j * 8 + hh);              // per-channel head weight
            o = fmaf(h1[(size_t)sj * 64 + lane], wj, o);   // coalesced 256B gather
        }
    }
    float outv = o + b1[lane];
    outv = outv > 0.f ? outv : __expf(outv) - 1.f;  // ELU fused
    elu1[(size_t)node * 64 + lane] = outv;
}

// ---------------- Layer 2 GEMM: h2 = elu1 @ W2 (whole-K in LDS) ----------------
__global__ __launch_bounds__(256) void gemm2_kernel(const float* __restrict__ elu1,
                                                    const float* __restrict__ W2,
                                                    float* __restrict__ h2, int n) {
    __shared__ float As[64][132];
    __shared__ float Bs[64][40];
    int tid = threadIdx.x;
    int r0 = blockIdx.x * 128;
    for (int t = tid; t < 640; t += 256) {
        int k = t / 10, cq = t % 10;
        *(float4*)&Bs[k][4 * cq] = *(const float4*)(W2 + (size_t)k * 40 + 4 * cq);
    }
    for (int t = tid; t < 2048; t += 256) {
        int row = t >> 4, kq = t & 15;
        int gr = r0 + row;
        float4 av = make_float4(0.f, 0.f, 0.f, 0.f);
        if (gr < n) av = *(const float4*)(elu1 + (size_t)gr * 64 + 4 * kq);
        As[4 * kq + 0][row] = av.x;
        As[4 * kq + 1][row] = av.y;
        As[4 * kq + 2][row] = av.z;
        As[4 * kq + 3][row] = av.w;
    }
    __syncthreads();
    int cx = tid & 7, ry = tid >> 3;
    float acc[4][5] = {{0.f}};
#pragma unroll 8
    for (int k = 0; k < 64; ++k) {
        float4 a = *(const float4*)&As[k][4 * ry];
        float ar[4] = {a.x, a.y, a.z, a.w};
        float br[5];
#pragma unroll
        for (int j = 0; j < 5; ++j) br[j] = Bs[k][5 * cx + j];
#pragma unroll
        for (int i = 0; i < 4; ++i)
#pragma unroll
            for (int j = 0; j < 5; ++j) acc[i][j] = fmaf(ar[i], br[j], acc[i][j]);
    }
#pragma unroll
    for (int i = 0; i < 4; ++i) {
        int gr = r0 + 4 * ry + i;
        if (gr < n) {
#pragma unroll
            for (int j = 0; j < 5; ++j) h2[(size_t)gr * 40 + 5 * cx + j] = acc[i][j];
        }
    }
}

// alpha2: per-node scalar dots
__global__ void alpha2_kernel(const float* __restrict__ h2, const float* __restrict__ att_s,
                              const float* __restrict__ att_d, float* __restrict__ as2,
                              float* __restrict__ ad2, int n) {
    int i = blockIdx.x * blockDim.x + threadIdx.x;
    if (i >= n) return;
    const float* row = h2 + (size_t)i * 40;
    float s = 0.f, d = 0.f;
#pragma unroll
    for (int c = 0; c < 40; ++c) {
        float v = row[c];
        s = fmaf(v, att_s[c], s);
        d = fmaf(v, att_d[c], d);
    }
    as2[i] = s;
    ad2[i] = d;
}

// ---------------- Layer 2 aggregation + bias + log_softmax ----------------
__global__ __launch_bounds__(256) void agg2_kernel(const float* __restrict__ h2,
                                                   const float* __restrict__ as2,
                                                   const float* __restrict__ ad2,
                                                   const float* __restrict__ b2,
                                                   const int* __restrict__ row_ptr,
                                                   const int* __restrict__ csr_src,
                                                   float* __restrict__ out, int n) {
    int lane = threadIdx.x & 63;
    int node = blockIdx.x * 4 + (threadIdx.x >> 6);
    if (node >= n) return;
    int start = row_ptr[node], end = row_ptr[node + 1];
    float adn = ad2[node];

    // pass 1: lane = edge
    float m = -1e30f, den = 0.f;
    for (int e0 = start; e0 < end; e0 += 64) {
        int e = e0 + lane;
        bool valid = e < end;
        int ee = valid ? e : end - 1;
        float v = lrelu(as2[csr_src[ee]] + adn);
        if (!valid) v = -INFINITY;
        float nm = fmaxf(m, v);
        den = den * __expf(m - nm) + __expf(v - nm);
        m = nm;
    }
#pragma unroll
    for (int off = 1; off < 64; off <<= 1) {
        float om = __shfl_xor(m, off);
        float od = __shfl_xor(den, off);
        float nm = fmaxf(m, om);
        den = den * __expf(m - nm) + od * __expf(om - nm);
        m = nm;
    }
    float inv = 1.f / den;

    // pass 2: compute w lane=edge, aggregate via scalar broadcast
    int c = min(lane, 39);
    float o = 0.f;
    for (int e0 = start; e0 < end; e0 += 64) {
        int e = e0 + lane;
        int ee = (e < end) ? e : end - 1;
        int s = csr_src[ee];
        float v = lrelu(as2[s] + adn);
        float w = __expf(v - m) * inv;
        int nv = min(64, end - e0);
        for (int j = 0; j < nv; ++j) {
            int sj = __builtin_amdgcn_readlane(s, j);
            float wj = rdlane_f(w, j);
            o = fmaf(h2[(size_t)sj * 40 + c], wj, o);
        }
    }
    float val = o + b2[c];
    float vm = (lane < 40) ? val : -1e30f;
#pragma unroll
    for (int off = 1; off < 64; off <<= 1) vm = fmaxf(vm, __shfl_xor(vm, off));
    float ex = (lane < 40) ? __expf(val - vm) : 0.f;
#pragma unroll
    for (int off = 1; off < 64; off <<= 1) ex += __shfl_xor(ex, off);
    if (lane < 40) out[(size_t)node * 40 + lane] = val - vm - __logf(ex);
}

// ---------------- launch ----------------
extern "C" void kernel_launch(void* const* d_in, const int* in_sizes, int n_in,
                              void* d_out, int out_size, void* d_ws, size_t ws_size,
                              hipStream_t stream) {
    const float* x        = (const float*)d_in[0];
    const float* W1       = (const float*)d_in[1];
    const float* att_src1 = (const float*)d_in[2];
    const float* att_dst1 = (const float*)d_in[3];
    const float* b1       = (const float*)d_in[4];
    const float* W2       = (const float*)d_in[5];
    const float* att_src2 = (const float*)d_in[6];
    const float* att_dst2 = (const float*)d_in[7];
    const float* b2       = (const float*)d_in[8];
    const int*   ei       = (const int*)d_in[9];

    int n    = in_sizes[0] / 256;   // 100000
    int etot = in_sizes[9] / 2;     // 1700000
    const int* srcp = ei;
    const int* dstp = ei + etot;

    char* ws = (char*)d_ws;
    size_t off = 0;
    float* h1   = (float*)(ws + off); off += (size_t)n * 64 * 4;   // reused as h2
    float* elu1 = (float*)(ws + off); off += (size_t)n * 64 * 4;
    float* as1  = (float*)(ws + off); off += (size_t)n * 8 * 4;
    float* ad1  = (float*)(ws + off); off += (size_t)n * 8 * 4;
    float* as2  = (float*)(ws + off); off += (size_t)n * 4;
    float* ad2  = (float*)(ws + off); off += (size_t)n * 4;
    int* row_ptr = (int*)(ws + off); off += (size_t)(n + 64) * 4;
    int* counts  = (int*)(ws + off); off += (size_t)n * 4;
    int* cursor  = (int*)(ws + off); off += (size_t)n * 4;
    int* bsums   = (int*)(ws + off); off += (size_t)2048 * 4;
    int* csr_src = (int*)(ws + off); off += (size_t)etot * 4;
    float* h2 = h1;
    float* outp = (float*)d_out;

    hipMemsetAsync(counts, 0, (size_t)n * 4, stream);
    int eb = (etot + 255) / 256;
    int nb256 = (n + 255) / 256;
    hist_kernel<<<eb, 256, 0, stream>>>(dstp, counts, etot);
    scanA_kernel<<<nb256, 256, 0, stream>>>(counts, bsums, n);
    scanB_kernel<<<1, 1024, 0, stream>>>(bsums, nb256);
    scanC_kernel<<<nb256, 256, 0, stream>>>(counts, bsums, row_ptr, cursor, n, etot);
    scatter_kernel<<<eb, 256, 0, stream>>>(srcp, dstp, cursor, csr_src, etot);

    int nb4 = (n + 3) / 4;
    gemm1_kernel<<<(n + 127) / 128, 256, 0, stream>>>(x, W1, h1, n);
    alpha1_kernel<<<512, 256, 0, stream>>>(h1, att_src1, att_dst1, as1, ad1, n);
    agg1_kernel<<<nb4, 256, 0, stream>>>(h1, as1, ad1, b1, row_ptr, csr_src, elu1, n);
    gemm2_kernel<<<(n + 127) / 128, 256, 0, stream>>>(elu1, W2, h2, n);
    alpha2_kernel<<<nb256, 256, 0, stream>>>(h2, att_src2, att_dst2, as2, ad2, n);
    agg2_kernel<<<nb4, 256, 0, stream>>>(h2, as2, ad2, b2, row_ptr, csr_src, outp, n);
}

// Round 4
// 556.271 us; speedup vs baseline: 2.5447x; 1.2676x over previous
//
#include <hip/hip_runtime.h>
#include <hip/hip_bf16.h>

#define NEG_SLOPE 0.2f

__device__ __forceinline__ float lrelu(float x) { return x >= 0.f ? x : NEG_SLOPE * x; }
__device__ __forceinline__ float rdlane_f(float v, int l) {
    return __int_as_float(__builtin_amdgcn_readlane(__float_as_int(v), l));
}

// ---------------- CSR build ----------------
__global__ void hist_kernel(const int* __restrict__ dst, int* __restrict__ counts, int etot) {
    int i = blockIdx.x * blockDim.x + threadIdx.x;
    if (i < etot) atomicAdd(&counts[dst[i]], 1);
}

__global__ __launch_bounds__(256) void scanA_kernel(const int* __restrict__ counts,
                                                    int* __restrict__ bsums, int n) {
    __shared__ int sm[256];
    int i = blockIdx.x * 256 + threadIdx.x;
    sm[threadIdx.x] = (i < n) ? counts[i] : 0;
    __syncthreads();
    for (int off = 128; off > 0; off >>= 1) {
        if (threadIdx.x < off) sm[threadIdx.x] += sm[threadIdx.x + off];
        __syncthreads();
    }
    if (threadIdx.x == 0) bsums[blockIdx.x] = sm[0];
}

__global__ __launch_bounds__(1024) void scanB_kernel(int* __restrict__ bsums, int nb) {
    __shared__ int sm[1024];
    int t = threadIdx.x;
    int v = (t < nb) ? bsums[t] : 0;
    sm[t] = v;
    __syncthreads();
    for (int off = 1; off < 1024; off <<= 1) {
        int u = (t >= off) ? sm[t - off] : 0;
        __syncthreads();
        sm[t] += u;
        __syncthreads();
    }
    if (t < nb) bsums[t] = sm[t] - v;  // exclusive
}

__global__ __launch_bounds__(256) void scanC_kernel(const int* __restrict__ counts,
                                                    const int* __restrict__ bsums,
                                                    int* __restrict__ row_ptr,
                                                    int* __restrict__ cursor, int n, int etot) {
    __shared__ int sm[256];
    int t = threadIdx.x;
    int i = blockIdx.x * 256 + t;
    int v = (i < n) ? counts[i] : 0;
    sm[t] = v;
    __syncthreads();
    for (int off = 1; off < 256; off <<= 1) {
        int u = (t >= off) ? sm[t - off] : 0;
        __syncthreads();
        sm[t] += u;
        __syncthreads();
    }
    if (i < n) {
        int ex = bsums[blockIdx.x] + sm[t] - v;
        row_ptr[i] = ex;
        cursor[i] = ex;
    }
    if (i == 0) row_ptr[n] = etot;
}

__global__ void scatter_kernel(const int* __restrict__ src, const int* __restrict__ dst,
                               int* __restrict__ cursor, int* __restrict__ csr_src, int etot) {
    int i = blockIdx.x * blockDim.x + threadIdx.x;
    if (i < etot) {
        int d = dst[i];
        int p = atomicAdd(&cursor[d], 1);
        csr_src[p] = src[i];
    }
}

// ---------------- Layer 1 GEMM: h1 = x @ W1 + fused alpha1 ----------------
__global__ __launch_bounds__(256) void gemm1_kernel(const float* __restrict__ x,
                                                    const float* __restrict__ W1,
                                                    const float* __restrict__ att_s,
                                                    const float* __restrict__ att_d,
                                                    float* __restrict__ h1,
                                                    float* __restrict__ as1,
                                                    float* __restrict__ ad1, int n) {
    __shared__ float As[16][132];
    __shared__ float Bs[16][64];
    int tid = threadIdx.x;
    int r0 = blockIdx.x * 128;
    int arow = tid >> 2, akq = tid & 3;
    int bk = tid >> 4, bcq = tid & 15;
    int tx = tid & 15, ty = tid >> 4;
    float4 s4 = *(const float4*)(att_s + 4 * tx);
    float4 dd4 = *(const float4*)(att_d + 4 * tx);
    float acc[8][4] = {{0.f}};
    for (int k0 = 0; k0 < 256; k0 += 16) {
        int g0 = r0 + arow, g1 = r0 + arow + 64;
        float4 av0 = make_float4(0.f, 0.f, 0.f, 0.f), av1 = av0;
        if (g0 < n) av0 = *(const float4*)(x + (size_t)g0 * 256 + k0 + 4 * akq);
        if (g1 < n) av1 = *(const float4*)(x + (size_t)g1 * 256 + k0 + 4 * akq);
        float4 bv = *(const float4*)(W1 + (size_t)(k0 + bk) * 64 + 4 * bcq);
        __syncthreads();
        As[4 * akq + 0][arow] = av0.x;
        As[4 * akq + 1][arow] = av0.y;
        As[4 * akq + 2][arow] = av0.z;
        As[4 * akq + 3][arow] = av0.w;
        As[4 * akq + 0][arow + 64] = av1.x;
        As[4 * akq + 1][arow + 64] = av1.y;
        As[4 * akq + 2][arow + 64] = av1.z;
        As[4 * akq + 3][arow + 64] = av1.w;
        *(float4*)&Bs[bk][4 * bcq] = bv;
        __syncthreads();
#pragma unroll
        for (int k = 0; k < 16; ++k) {
            float4 a0 = *(const float4*)&As[k][8 * ty];
            float4 a1 = *(const float4*)&As[k][8 * ty + 4];
            float4 b = *(const float4*)&Bs[k][4 * tx];
            float ar[8] = {a0.x, a0.y, a0.z, a0.w, a1.x, a1.y, a1.z, a1.w};
            float br[4] = {b.x, b.y, b.z, b.w};
#pragma unroll
            for (int i = 0; i < 8; ++i)
#pragma unroll
                for (int j = 0; j < 4; ++j) acc[i][j] = fmaf(ar[i], br[j], acc[i][j]);
        }
    }
#pragma unroll
    for (int i = 0; i < 8; ++i) {
        int gr = r0 + 8 * ty + i;
        float4 o = make_float4(acc[i][0], acc[i][1], acc[i][2], acc[i][3]);
        float ps = acc[i][0] * s4.x + acc[i][1] * s4.y + acc[i][2] * s4.z + acc[i][3] * s4.w;
        float pd = acc[i][0] * dd4.x + acc[i][1] * dd4.y + acc[i][2] * dd4.z + acc[i][3] * dd4.w;
        ps += __shfl_xor(ps, 1);   // pair lanes cover the full 8-col head
        pd += __shfl_xor(pd, 1);
        if (gr < n) {
            *(float4*)(h1 + (size_t)gr * 64 + 4 * tx) = o;
            if ((tx & 1) == 0) {
                as1[(size_t)gr * 8 + (tx >> 1)] = ps;
                ad1[(size_t)gr * 8 + (tx >> 1)] = pd;
            }
        }
    }
}

// ---------------- Layer 1 aggregation ----------------
// Chunked coalesced csr_src load + shfl; pass1 16 edges/iter (2 gathers in flight);
// pass2 fixed-8 unrolled gathers (8 in flight).
__global__ __launch_bounds__(256) void agg1_kernel(const float* __restrict__ h1,
                                                   const float* __restrict__ as1,
                                                   const float* __restrict__ ad1,
                                                   const float* __restrict__ b1,
                                                   const int* __restrict__ row_ptr,
                                                   const int* __restrict__ csr_src,
                                                   float* __restrict__ elu1, int n) {
    int lane = threadIdx.x & 63;
    int node = blockIdx.x * 4 + (threadIdx.x >> 6);
    if (node >= n) return;
    int start = row_ptr[node], end = row_ptr[node + 1];
    int slot = lane >> 3, hd = lane & 7;
    float adh = ad1[(size_t)node * 8 + hd];

    // pass 1: online softmax, (slot,head) layout, 16 edges per iteration
    float m = -1e30f, den = 0.f;
    for (int base = start; base < end; base += 64) {
        int nloc = min(64, end - base);
        int eidx = base + lane;
        int sAll = (eidx < end) ? csr_src[eidx] : 0;  // coalesced
        for (int e0 = 0; e0 < nloc; e0 += 16) {
            int s0 = __shfl(sAll, e0 + slot);
            int s1 = __shfl(sAll, e0 + 8 + slot);
            float v0 = lrelu(as1[(size_t)s0 * 8 + hd] + adh);
            float v1 = lrelu(as1[(size_t)s1 * 8 + hd] + adh);
            if (e0 + slot >= nloc) v0 = -INFINITY;
            if (e0 + 8 + slot >= nloc) v1 = -INFINITY;
            float nm = fmaxf(m, fmaxf(v0, v1));
            den = den * __expf(m - nm) + __expf(v0 - nm) + __expf(v1 - nm);
            m = nm;
        }
    }
#pragma unroll
    for (int off = 8; off < 64; off <<= 1) {  // merge across slots
        float om = __shfl_xor(m, off);
        float od = __shfl_xor(den, off);
        float nm = fmaxf(m, om);
        den = den * __expf(m - nm) + od * __expf(om - nm);
        m = nm;
    }
    float inv = 1.f / den;

    // pass 2: weights in (slot,head) layout, lane = channel for gather; 8 gathers in flight
    int hh = lane >> 3;
    float o = 0.f;
    for (int base = start; base < end; base += 64) {
        int nloc = min(64, end - base);
        int eidx = base + lane;
        int sAll = (eidx < end) ? csr_src[eidx] : 0;
        for (int e0 = 0; e0 < nloc; e0 += 8) {
            int s = __shfl(sAll, e0 + slot);
            float v = lrelu(as1[(size_t)s * 8 + hd] + adh);
            float w = (e0 + slot < nloc) ? __expf(v - m) * inv : 0.f;
#pragma unroll
            for (int j = 0; j < 8; ++j) {
                int sj = __builtin_amdgcn_readlane(s, j * 8);  // garbage rows get w=0
                float wj = __shfl(w, j * 8 + hh);
                o = fmaf(h1[(size_t)sj * 64 + lane], wj, o);   // coalesced 256B gather
            }
        }
    }
    float outv = o + b1[lane];
    outv = outv > 0.f ? outv : __expf(outv) - 1.f;  // ELU fused
    elu1[(size_t)node * 64 + lane] = outv;
}

// ---------------- Layer 2 GEMM: h2 = elu1 @ W2 + fused alpha2 ----------------
__global__ __launch_bounds__(256) void gemm2_kernel(const float* __restrict__ elu1,
                                                    const float* __restrict__ W2,
                                                    const float* __restrict__ att_s,
                                                    const float* __restrict__ att_d,
                                                    float* __restrict__ h2,
                                                    float* __restrict__ as2,
                                                    float* __restrict__ ad2, int n) {
    __shared__ float As[64][132];
    __shared__ float Bs[64][40];
    int tid = threadIdx.x;
    int r0 = blockIdx.x * 128;
    int cx = tid & 7, ry = tid >> 3;
    float sa[5], da[5];
#pragma unroll
    for (int j = 0; j < 5; ++j) {
        sa[j] = att_s[5 * cx + j];
        da[j] = att_d[5 * cx + j];
    }
    for (int t = tid; t < 640; t += 256) {
        int k = t / 10, cq = t % 10;
        *(float4*)&Bs[k][4 * cq] = *(const float4*)(W2 + (size_t)k * 40 + 4 * cq);
    }
    for (int t = tid; t < 2048; t += 256) {
        int row = t >> 4, kq = t & 15;
        int gr = r0 + row;
        float4 av = make_float4(0.f, 0.f, 0.f, 0.f);
        if (gr < n) av = *(const float4*)(elu1 + (size_t)gr * 64 + 4 * kq);
        As[4 * kq + 0][row] = av.x;
        As[4 * kq + 1][row] = av.y;
        As[4 * kq + 2][row] = av.z;
        As[4 * kq + 3][row] = av.w;
    }
    __syncthreads();
    float acc[4][5] = {{0.f}};
#pragma unroll 8
    for (int k = 0; k < 64; ++k) {
        float4 a = *(const float4*)&As[k][4 * ry];
        float ar[4] = {a.x, a.y, a.z, a.w};
        float br[5];
#pragma unroll
        for (int j = 0; j < 5; ++j) br[j] = Bs[k][5 * cx + j];
#pragma unroll
        for (int i = 0; i < 4; ++i)
#pragma unroll
            for (int j = 0; j < 5; ++j) acc[i][j] = fmaf(ar[i], br[j], acc[i][j]);
    }
#pragma unroll
    for (int i = 0; i < 4; ++i) {
        int gr = r0 + 4 * ry + i;
        float ps = 0.f, pd = 0.f;
#pragma unroll
        for (int j = 0; j < 5; ++j) {
            ps = fmaf(acc[i][j], sa[j], ps);
            pd = fmaf(acc[i][j], da[j], pd);
        }
        ps += __shfl_xor(ps, 1); pd += __shfl_xor(pd, 1);
        ps += __shfl_xor(ps, 2); pd += __shfl_xor(pd, 2);
        ps += __shfl_xor(ps, 4); pd += __shfl_xor(pd, 4);
        if (gr < n) {
#pragma unroll
            for (int j = 0; j < 5; ++j) h2[(size_t)gr * 40 + 5 * cx + j] = acc[i][j];
            if (cx == 0) {
                as2[gr] = ps;
                ad2[gr] = pd;
            }
        }
    }
}

// ---------------- Layer 2 aggregation + bias + log_softmax ----------------
__global__ __launch_bounds__(256) void agg2_kernel(const float* __restrict__ h2,
                                                   const float* __restrict__ as2,
                                                   const float* __restrict__ ad2,
                                                   const float* __restrict__ b2,
                                                   const int* __restrict__ row_ptr,
                                                   const int* __restrict__ csr_src,
                                                   float* __restrict__ out, int n) {
    int lane = threadIdx.x & 63;
    int node = blockIdx.x * 4 + (threadIdx.x >> 6);
    if (node >= n) return;
    int start = row_ptr[node], end = row_ptr[node + 1];
    float adn = ad2[node];

    // pass 1: lane = edge, chunked coalesced
    float m = -1e30f, den = 0.f;
    for (int base = start; base < end; base += 64) {
        int eidx = base + lane;
        bool valid = eidx < end;
        int s = valid ? csr_src[eidx] : 0;
        float v = lrelu(as2[s] + adn);
        if (!valid) v = -INFINITY;
        float nm = fmaxf(m, v);
        den = den * __expf(m - nm) + __expf(v - nm);
        m = nm;
    }
#pragma unroll
    for (int off = 1; off < 64; off <<= 1) {
        float om = __shfl_xor(m, off);
        float od = __shfl_xor(den, off);
        float nm = fmaxf(m, om);
        den = den * __expf(m - nm) + od * __expf(om - nm);
        m = nm;
    }
    float inv = 1.f / den;

    // pass 2: fixed-8 unrolled gathers per group
    int c = min(lane, 39);
    float o = 0.f;
    for (int base = start; base < end; base += 64) {
        int nloc = min(64, end - base);
        int eidx = base + lane;
        bool valid = eidx < end;
        int sAll = valid ? csr_src[eidx] : 0;
        float v = lrelu(as2[sAll] + adn);
        float w = valid ? __expf(v - m) * inv : 0.f;
        for (int g = 0; g * 8 < nloc; ++g) {
#pragma unroll
            for (int j = 0; j < 8; ++j) {
                int jj = g * 8 + j;
                int sj = __builtin_amdgcn_readlane(sAll, jj);
                float wj = rdlane_f(w, jj);
                o = fmaf(h2[(size_t)sj * 40 + c], wj, o);
            }
        }
    }
    float val = o + b2[c];
    float vm = (lane < 40) ? val : -1e30f;
#pragma unroll
    for (int off = 1; off < 64; off <<= 1) vm = fmaxf(vm, __shfl_xor(vm, off));
    float ex = (lane < 40) ? __expf(val - vm) : 0.f;
#pragma unroll
    for (int off = 1; off < 64; off <<= 1) ex += __shfl_xor(ex, off);
    if (lane < 40) out[(size_t)node * 40 + lane] = val - vm - __logf(ex);
}

// ---------------- launch ----------------
extern "C" void kernel_launch(void* const* d_in, const int* in_sizes, int n_in,
                              void* d_out, int out_size, void* d_ws, size_t ws_size,
                              hipStream_t stream) {
    const float* x        = (const float*)d_in[0];
    const float* W1       = (const float*)d_in[1];
    const float* att_src1 = (const float*)d_in[2];
    const float* att_dst1 = (const float*)d_in[3];
    const float* b1       = (const float*)d_in[4];
    const float* W2       = (const float*)d_in[5];
    const float* att_src2 = (const float*)d_in[6];
    const float* att_dst2 = (const float*)d_in[7];
    const float* b2       = (const float*)d_in[8];
    const int*   ei       = (const int*)d_in[9];

    int n    = in_sizes[0] / 256;   // 100000
    int etot = in_sizes[9] / 2;     // 1700000
    const int* srcp = ei;
    const int* dstp = ei + etot;

    char* ws = (char*)d_ws;
    size_t off = 0;
    float* h1   = (float*)(ws + off); off += (size_t)n * 64 * 4;   // reused as h2
    float* elu1 = (float*)(ws + off); off += (size_t)n * 64 * 4;
    float* as1  = (float*)(ws + off); off += (size_t)n * 8 * 4;
    float* ad1  = (float*)(ws + off); off += (size_t)n * 8 * 4;
    float* as2  = (float*)(ws + off); off += (size_t)n * 4;
    float* ad2  = (float*)(ws + off); off += (size_t)n * 4;
    int* row_ptr = (int*)(ws + off); off += (size_t)(n + 64) * 4;
    int* counts  = (int*)(ws + off); off += (size_t)n * 4;
    int* cursor  = (int*)(ws + off); off += (size_t)n * 4;
    int* bsums   = (int*)(ws + off); off += (size_t)2048 * 4;
    int* csr_src = (int*)(ws + off); off += (size_t)etot * 4;
    float* h2 = h1;
    float* outp = (float*)d_out;

    hipMemsetAsync(counts, 0, (size_t)n * 4, stream);
    int eb = (etot + 255) / 256;
    int nb256 = (n + 255) / 256;
    hist_kernel<<<eb, 256, 0, stream>>>(dstp, counts, etot);
    scanA_kernel<<<nb256, 256, 0, stream>>>(counts, bsums, n);
    scanB_kernel<<<1, 1024, 0, stream>>>(bsums, nb256);
    scanC_kernel<<<nb256, 256, 0, stream>>>(counts, bsums, row_ptr, cursor, n, etot);
    scatter_kernel<<<eb, 256, 0, stream>>>(srcp, dstp, cursor, csr_src, etot);

    int nb4 = (n + 3) / 4;
    gemm1_kernel<<<(n + 127) / 128, 256, 0, stream>>>(x, W1, att_src1, att_dst1, h1, as1, ad1, n);
    agg1_kernel<<<nb4, 256, 0, stream>>>(h1, as1, ad1, b1, row_ptr, csr_src, elu1, n);
    gemm2_kernel<<<(n + 127) / 128, 256, 0, stream>>>(elu1, W2, att_src2, att_dst2, h2, as2, ad2, n);
    agg2_kernel<<<nb4, 256, 0, stream>>>(h2, as2, ad2, b2, row_ptr, csr_src, outp, n);
}

// Round 5
// 494.724 us; speedup vs baseline: 2.8612x; 1.1244x over previous
//
#include <hip/hip_runtime.h>
#include <hip/hip_bf16.h>

#define NEG_SLOPE 0.2f

__device__ __forceinline__ float lrelu(float x) { return x >= 0.f ? x : NEG_SLOPE * x; }

// pack two fp32 -> bf16x2 (RNE), low = a, high = b
__device__ __forceinline__ unsigned pack_bf2(float a, float b) {
    unsigned ua = __float_as_uint(a), ub = __float_as_uint(b);
    ua = (ua + 0x7fffu + ((ua >> 16) & 1u)) >> 16;
    ub = (ub + 0x7fffu + ((ub >> 16) & 1u)) & 0xffff0000u;
    return ua | ub;
}
__device__ __forceinline__ float2 unpack_bf2(unsigned u) {
    return make_float2(__uint_as_float(u << 16), __uint_as_float(u & 0xffff0000u));
}
__device__ __forceinline__ unsigned short bf16_of(float a) {
    unsigned ua = __float_as_uint(a);
    return (unsigned short)((ua + 0x7fffu + ((ua >> 16) & 1u)) >> 16);
}

// ---------------- CSR build (XCD-partitioned: part = blockIdx & 7) ----------------
__global__ __launch_bounds__(256) void hist_kernel(const int* __restrict__ dst,
                                                   int* __restrict__ counts, int etot, int n) {
    int part = blockIdx.x & 7;
    int stripe = blockIdx.x >> 3;
    int nstripes = gridDim.x >> 3;
    int psz = (n + 7) >> 3;
    int lo = part * psz, hi = min(n, lo + psz);
    int per = (etot + nstripes - 1) / nstripes;
    int e0 = stripe * per, e1 = min(etot, e0 + per);
    for (int e = e0 + (int)threadIdx.x; e < e1; e += 256) {
        int d = dst[e];
        if (d >= lo && d < hi) atomicAdd(&counts[d], 1);
    }
}

__global__ __launch_bounds__(256) void scanA_kernel(const int* __restrict__ counts,
                                                    int* __restrict__ bsums, int n) {
    __shared__ int sm[256];
    int i = blockIdx.x * 256 + threadIdx.x;
    sm[threadIdx.x] = (i < n) ? counts[i] : 0;
    __syncthreads();
    for (int off = 128; off > 0; off >>= 1) {
        if (threadIdx.x < off) sm[threadIdx.x] += sm[threadIdx.x + off];
        __syncthreads();
    }
    if (threadIdx.x == 0) bsums[blockIdx.x] = sm[0];
}

__global__ __launch_bounds__(1024) void scanB_kernel(int* __restrict__ bsums, int nb) {
    __shared__ int sm[1024];
    int t = threadIdx.x;
    int v = (t < nb) ? bsums[t] : 0;
    sm[t] = v;
    __syncthreads();
    for (int off = 1; off < 1024; off <<= 1) {
        int u = (t >= off) ? sm[t - off] : 0;
        __syncthreads();
        sm[t] += u;
        __syncthreads();
    }
    if (t < nb) bsums[t] = sm[t] - v;  // exclusive
}

__global__ __launch_bounds__(256) void scanC_kernel(const int* __restrict__ counts,
                                                    const int* __restrict__ bsums,
                                                    int* __restrict__ row_ptr,
                                                    int* __restrict__ cursor, int n, int etot) {
    __shared__ int sm[256];
    int t = threadIdx.x;
    int i = blockIdx.x * 256 + t;
    int v = (i < n) ? counts[i] : 0;
    sm[t] = v;
    __syncthreads();
    for (int off = 1; off < 256; off <<= 1) {
        int u = (t >= off) ? sm[t - off] : 0;
        __syncthreads();
        sm[t] += u;
        __syncthreads();
    }
    if (i < n) {
        int ex = bsums[blockIdx.x] + sm[t] - v;
        row_ptr[i] = ex;
        cursor[i] = ex;
    }
    if (i == 0) row_ptr[n] = etot;
}

__global__ __launch_bounds__(256) void scatter_kernel(const int* __restrict__ src,
                                                      const int* __restrict__ dst,
                                                      int* __restrict__ cursor,
                                                      int* __restrict__ csr_src, int etot, int n) {
    int part = blockIdx.x & 7;
    int stripe = blockIdx.x >> 3;
    int nstripes = gridDim.x >> 3;
    int psz = (n + 7) >> 3;
    int lo = part * psz, hi = min(n, lo + psz);
    int per = (etot + nstripes - 1) / nstripes;
    int e0 = stripe * per, e1 = min(etot, e0 + per);
    for (int e = e0 + (int)threadIdx.x; e < e1; e += 256) {
        int d = dst[e];
        if (d >= lo && d < hi) {
            int p = atomicAdd(&cursor[d], 1);
            csr_src[p] = src[e];
        }
    }
}

// ---------------- Layer 1 GEMM: h1(bf16) = x @ W1, fused alpha1 ----------------
__global__ __launch_bounds__(256) void gemm1_kernel(const float* __restrict__ x,
                                                    const float* __restrict__ W1,
                                                    const float* __restrict__ att_s,
                                                    const float* __restrict__ att_d,
                                                    unsigned short* __restrict__ h1b,
                                                    float* __restrict__ as1,
                                                    float* __restrict__ ad1, int n) {
    __shared__ float As[16][132];
    __shared__ float Bs[16][64];
    int tid = threadIdx.x;
    int r0 = blockIdx.x * 128;
    int arow = tid >> 2, akq = tid & 3;
    int bk = tid >> 4, bcq = tid & 15;
    int tx = tid & 15, ty = tid >> 4;
    float4 s4 = *(const float4*)(att_s + 4 * tx);
    float4 dd4 = *(const float4*)(att_d + 4 * tx);
    float acc[8][4] = {{0.f}};
    for (int k0 = 0; k0 < 256; k0 += 16) {
        int g0 = r0 + arow, g1 = r0 + arow + 64;
        float4 av0 = make_float4(0.f, 0.f, 0.f, 0.f), av1 = av0;
        if (g0 < n) av0 = *(const float4*)(x + (size_t)g0 * 256 + k0 + 4 * akq);
        if (g1 < n) av1 = *(const float4*)(x + (size_t)g1 * 256 + k0 + 4 * akq);
        float4 bv = *(const float4*)(W1 + (size_t)(k0 + bk) * 64 + 4 * bcq);
        __syncthreads();
        As[4 * akq + 0][arow] = av0.x;
        As[4 * akq + 1][arow] = av0.y;
        As[4 * akq + 2][arow] = av0.z;
        As[4 * akq + 3][arow] = av0.w;
        As[4 * akq + 0][arow + 64] = av1.x;
        As[4 * akq + 1][arow + 64] = av1.y;
        As[4 * akq + 2][arow + 64] = av1.z;
        As[4 * akq + 3][arow + 64] = av1.w;
        *(float4*)&Bs[bk][4 * bcq] = bv;
        __syncthreads();
#pragma unroll
        for (int k = 0; k < 16; ++k) {
            float4 a0 = *(const float4*)&As[k][8 * ty];
            float4 a1 = *(const float4*)&As[k][8 * ty + 4];
            float4 b = *(const float4*)&Bs[k][4 * tx];
            float ar[8] = {a0.x, a0.y, a0.z, a0.w, a1.x, a1.y, a1.z, a1.w};
            float br[4] = {b.x, b.y, b.z, b.w};
#pragma unroll
            for (int i = 0; i < 8; ++i)
#pragma unroll
                for (int j = 0; j < 4; ++j) acc[i][j] = fmaf(ar[i], br[j], acc[i][j]);
        }
    }
#pragma unroll
    for (int i = 0; i < 8; ++i) {
        int gr = r0 + 8 * ty + i;
        float ps = acc[i][0] * s4.x + acc[i][1] * s4.y + acc[i][2] * s4.z + acc[i][3] * s4.w;
        float pd = acc[i][0] * dd4.x + acc[i][1] * dd4.y + acc[i][2] * dd4.z + acc[i][3] * dd4.w;
        ps += __shfl_xor(ps, 1);  // pair lanes cover the 8-col head
        pd += __shfl_xor(pd, 1);
        if (gr < n) {
            uint2 u;
            u.x = pack_bf2(acc[i][0], acc[i][1]);
            u.y = pack_bf2(acc[i][2], acc[i][3]);
            *(uint2*)(h1b + (size_t)gr * 64 + 4 * tx) = u;
            if ((tx & 1) == 0) {
                as1[(size_t)gr * 8 + (tx >> 1)] = ps;
                ad1[(size_t)gr * 8 + (tx >> 1)] = pd;
            }
        }
    }
}

// ---------------- Layer 1 aggregation ----------------
__global__ __launch_bounds__(256) void agg1_kernel(const unsigned short* __restrict__ h1b,
                                                   const float* __restrict__ as1,
                                                   const float* __restrict__ ad1,
                                                   const float* __restrict__ b1,
                                                   const int* __restrict__ row_ptr,
                                                   const int* __restrict__ csr_src,
                                                   float* __restrict__ elu1, int n) {
    int lane = threadIdx.x & 63;
    int node = blockIdx.x * 4 + (threadIdx.x >> 6);
    if (node >= n) return;
    int start = row_ptr[node], end = row_ptr[node + 1];
    int slot = lane >> 3, hd = lane & 7;
    float adh = ad1[(size_t)node * 8 + hd];

    // pass 1: online softmax, (slot,head) layout, 16 edges/iter
    float m = -1e30f, den = 0.f;
    for (int base = start; base < end; base += 64) {
        int nloc = min(64, end - base);
        int eidx = base + lane;
        int sAll = (eidx < end) ? csr_src[eidx] : 0;  // coalesced
        for (int e0 = 0; e0 < nloc; e0 += 16) {
            int s0 = __shfl(sAll, e0 + slot);
            int s1 = __shfl(sAll, e0 + 8 + slot);
            float v0 = lrelu(as1[(size_t)s0 * 8 + hd] + adh);
            float v1 = lrelu(as1[(size_t)s1 * 8 + hd] + adh);
            if (e0 + slot >= nloc) v0 = -INFINITY;
            if (e0 + 8 + slot >= nloc) v1 = -INFINITY;
            float nm = fmaxf(m, fmaxf(v0, v1));
            den = den * __expf(m - nm) + __expf(v0 - nm) + __expf(v1 - nm);
            m = nm;
        }
    }
#pragma unroll
    for (int off = 8; off < 64; off <<= 1) {
        float om = __shfl_xor(m, off);
        float od = __shfl_xor(den, off);
        float nm = fmaxf(m, om);
        den = den * __expf(m - nm) + od * __expf(om - nm);
        m = nm;
    }
    float inv = 1.f / den;

    // pass 2: bf16 gather, channel-pair lanes, 2 edges per gather instr
    int q = lane >> 5, p = lane & 31, hp = p >> 2;  // channels (2p,2p+1), head = p>>2
    const unsigned* h1u = (const unsigned*)h1b;     // row stride 32 uints (128B)
    float2 o = make_float2(0.f, 0.f);
    for (int base = start; base < end; base += 64) {
        int nloc = min(64, end - base);
        int eidx = base + lane;
        int sAll = (eidx < end) ? csr_src[eidx] : 0;
        for (int e0 = 0; e0 < nloc; e0 += 8) {
            int s = __shfl(sAll, e0 + slot);  // (slot,hd) layout
            float v = lrelu(as1[(size_t)s * 8 + hd] + adh);
            float w = (e0 + slot < nloc) ? __expf(v - m) * inv : 0.f;
#pragma unroll
            for (int j = 0; j < 8; j += 2) {
                int sj = __shfl(s, (j + q) * 8);
                float wj = __shfl(w, (j + q) * 8 + hp);
                float2 hf = unpack_bf2(h1u[(size_t)sj * 32 + p]);
                o.x = fmaf(hf.x, wj, o.x);
                o.y = fmaf(hf.y, wj, o.y);
            }
        }
    }
    o.x += __shfl_xor(o.x, 32);
    o.y += __shfl_xor(o.y, 32);
    if (lane < 32) {
        float2 bb = *(const float2*)(b1 + 2 * p);
        float v0 = o.x + bb.x, v1 = o.y + bb.y;
        v0 = v0 > 0.f ? v0 : __expf(v0) - 1.f;
        v1 = v1 > 0.f ? v1 : __expf(v1) - 1.f;
        *(float2*)(elu1 + (size_t)node * 64 + 2 * p) = make_float2(v0, v1);
    }
}

// ---------------- Layer 2 GEMM: h2(bf16) = elu1 @ W2, fused alpha2 ----------------
__global__ __launch_bounds__(256) void gemm2_kernel(const float* __restrict__ elu1,
                                                    const float* __restrict__ W2,
                                                    const float* __restrict__ att_s,
                                                    const float* __restrict__ att_d,
                                                    unsigned short* __restrict__ h2b,
                                                    float* __restrict__ as2,
                                                    float* __restrict__ ad2, int n) {
    __shared__ float As[64][132];
    __shared__ float Bs[64][40];
    int tid = threadIdx.x;
    int r0 = blockIdx.x * 128;
    int cx = tid & 7, ry = tid >> 3;
    float sa[5], da[5];
#pragma unroll
    for (int j = 0; j < 5; ++j) {
        sa[j] = att_s[5 * cx + j];
        da[j] = att_d[5 * cx + j];
    }
    for (int t = tid; t < 640; t += 256) {
        int k = t / 10, cq = t % 10;
        *(float4*)&Bs[k][4 * cq] = *(const float4*)(W2 + (size_t)k * 40 + 4 * cq);
    }
    for (int t = tid; t < 2048; t += 256) {
        int row = t >> 4, kq = t & 15;
        int gr = r0 + row;
        float4 av = make_float4(0.f, 0.f, 0.f, 0.f);
        if (gr < n) av = *(const float4*)(elu1 + (size_t)gr * 64 + 4 * kq);
        As[4 * kq + 0][row] = av.x;
        As[4 * kq + 1][row] = av.y;
        As[4 * kq + 2][row] = av.z;
        As[4 * kq + 3][row] = av.w;
    }
    __syncthreads();
    float acc[4][5] = {{0.f}};
#pragma unroll 8
    for (int k = 0; k < 64; ++k) {
        float4 a = *(const float4*)&As[k][4 * ry];
        float ar[4] = {a.x, a.y, a.z, a.w};
        float br[5];
#pragma unroll
        for (int j = 0; j < 5; ++j) br[j] = Bs[k][5 * cx + j];
#pragma unroll
        for (int i = 0; i < 4; ++i)
#pragma unroll
            for (int j = 0; j < 5; ++j) acc[i][j] = fmaf(ar[i], br[j], acc[i][j]);
    }
#pragma unroll
    for (int i = 0; i < 4; ++i) {
        int gr = r0 + 4 * ry + i;
        float ps = 0.f, pd = 0.f;
#pragma unroll
        for (int j = 0; j < 5; ++j) {
            ps = fmaf(acc[i][j], sa[j], ps);
            pd = fmaf(acc[i][j], da[j], pd);
        }
        ps += __shfl_xor(ps, 1); pd += __shfl_xor(pd, 1);
        ps += __shfl_xor(ps, 2); pd += __shfl_xor(pd, 2);
        ps += __shfl_xor(ps, 4); pd += __shfl_xor(pd, 4);
        if (gr < n) {
#pragma unroll
            for (int j = 0; j < 5; ++j) h2b[(size_t)gr * 40 + 5 * cx + j] = bf16_of(acc[i][j]);
            if (cx == 0) {
                as2[gr] = ps;
                ad2[gr] = pd;
            }
        }
    }
}

// ---------------- Layer 2 aggregation + bias + log_softmax ----------------
__global__ __launch_bounds__(256) void agg2_kernel(const unsigned short* __restrict__ h2b,
                                                   const float* __restrict__ as2,
                                                   const float* __restrict__ ad2,
                                                   const float* __restrict__ b2,
                                                   const int* __restrict__ row_ptr,
                                                   const int* __restrict__ csr_src,
                                                   float* __restrict__ out, int n) {
    int lane = threadIdx.x & 63;
    int node = blockIdx.x * 4 + (threadIdx.x >> 6);
    if (node >= n) return;
    int start = row_ptr[node], end = row_ptr[node + 1];
    float adn = ad2[node];

    // pass 1: lane = edge
    float m = -1e30f, den = 0.f;
    for (int base = start; base < end; base += 64) {
        int eidx = base + lane;
        bool valid = eidx < end;
        int s = valid ? csr_src[eidx] : 0;
        float v = lrelu(as2[s] + adn);
        if (!valid) v = -INFINITY;
        float nm = fmaxf(m, v);
        den = den * __expf(m - nm) + __expf(v - nm);
        m = nm;
    }
#pragma unroll
    for (int off = 1; off < 64; off <<= 1) {
        float om = __shfl_xor(m, off);
        float od = __shfl_xor(den, off);
        float nm = fmaxf(m, om);
        den = den * __expf(m - nm) + od * __expf(om - nm);
        m = nm;
    }
    float inv = 1.f / den;

    // pass 2: bf16 gather, channel-pair lanes, 2 edges per gather instr
    int q = lane >> 5, p = lane & 31;
    int pc = min(p, 19);
    const unsigned* h2u = (const unsigned*)h2b;  // row stride 20 uints (80B)
    float2 o = make_float2(0.f, 0.f);
    for (int base = start; base < end; base += 64) {
        int nloc = min(64, end - base);
        int eidx = base + lane;
        bool valid = eidx < end;
        int sAll = valid ? csr_src[eidx] : 0;
        float v = lrelu(as2[sAll] + adn);
        float w = valid ? __expf(v - m) * inv : 0.f;
        for (int g = 0; g < nloc; g += 8) {
#pragma unroll
            for (int j = 0; j < 8; j += 2) {
                int idx = g + j + q;
                int sj = __shfl(sAll, idx);
                float wj = __shfl(w, idx);
                float2 hf = unpack_bf2(h2u[(size_t)sj * 20 + pc]);
                o.x = fmaf(hf.x, wj, o.x);
                o.y = fmaf(hf.y, wj, o.y);
            }
        }
    }
    o.x += __shfl_xor(o.x, 32);
    o.y += __shfl_xor(o.y, 32);
    bool act = (lane < 32) && (p < 20);
    float v0 = -1e30f, v1 = -1e30f;
    if (act) {
        float2 bb = *(const float2*)(b2 + 2 * p);
        v0 = o.x + bb.x;
        v1 = o.y + bb.y;
    }
    float vm = fmaxf(v0, v1);
#pragma unroll
    for (int off = 1; off < 64; off <<= 1) vm = fmaxf(vm, __shfl_xor(vm, off));
    float ex = act ? (__expf(v0 - vm) + __expf(v1 - vm)) : 0.f;
#pragma unroll
    for (int off = 1; off < 64; off <<= 1) ex += __shfl_xor(ex, off);
    if (act) {
        float lg = __logf(ex);
        *(float2*)(out + (size_t)node * 40 + 2 * p) = make_float2(v0 - vm - lg, v1 - vm - lg);
    }
}

// ---------------- launch ----------------
extern "C" void kernel_launch(void* const* d_in, const int* in_sizes, int n_in,
                              void* d_out, int out_size, void* d_ws, size_t ws_size,
                              hipStream_t stream) {
    const float* x        = (const float*)d_in[0];
    const float* W1       = (const float*)d_in[1];
    const float* att_src1 = (const float*)d_in[2];
    const float* att_dst1 = (const float*)d_in[3];
    const float* b1       = (const float*)d_in[4];
    const float* W2       = (const float*)d_in[5];
    const float* att_src2 = (const float*)d_in[6];
    const float* att_dst2 = (const float*)d_in[7];
    const float* b2       = (const float*)d_in[8];
    const int*   ei       = (const int*)d_in[9];

    int n    = in_sizes[0] / 256;   // 100000
    int etot = in_sizes[9] / 2;     // 1700000
    const int* srcp = ei;
    const int* dstp = ei + etot;

    char* ws = (char*)d_ws;
    size_t off = 0;
    unsigned short* h1b = (unsigned short*)(ws + off); off += (size_t)n * 64 * 2;
    unsigned short* h2b = (unsigned short*)(ws + off); off += (size_t)n * 40 * 2;
    float* elu1 = (float*)(ws + off); off += (size_t)n * 64 * 4;
    float* as1  = (float*)(ws + off); off += (size_t)n * 8 * 4;
    float* ad1  = (float*)(ws + off); off += (size_t)n * 8 * 4;
    float* as2  = (float*)(ws + off); off += (size_t)n * 4;
    float* ad2  = (float*)(ws + off); off += (size_t)n * 4;
    int* row_ptr = (int*)(ws + off); off += (size_t)(n + 64) * 4;
    int* counts  = (int*)(ws + off); off += (size_t)n * 4;
    int* cursor  = (int*)(ws + off); off += (size_t)n * 4;
    int* bsums   = (int*)(ws + off); off += (size_t)2048 * 4;
    int* csr_src = (int*)(ws + off); off += (size_t)etot * 4;
    float* outp = (float*)d_out;

    hipMemsetAsync(counts, 0, (size_t)n * 4, stream);
    int nb256 = (n + 255) / 256;
    // 8 XCD-partitions x 256 stripes
    hist_kernel<<<2048, 256, 0, stream>>>(dstp, counts, etot, n);
    scanA_kernel<<<nb256, 256, 0, stream>>>(counts, bsums, n);
    scanB_kernel<<<1, 1024, 0, stream>>>(bsums, nb256);
    scanC_kernel<<<nb256, 256, 0, stream>>>(counts, bsums, row_ptr, cursor, n, etot);
    scatter_kernel<<<2048, 256, 0, stream>>>(srcp, dstp, cursor, csr_src, etot, n);

    int nb4 = (n + 3) / 4;
    gemm1_kernel<<<(n + 127) / 128, 256, 0, stream>>>(x, W1, att_src1, att_dst1, h1b, as1, ad1, n);
    agg1_kernel<<<nb4, 256, 0, stream>>>(h1b, as1, ad1, b1, row_ptr, csr_src, elu1, n);
    gemm2_kernel<<<(n + 127) / 128, 256, 0, stream>>>(elu1, W2, att_src2, att_dst2, h2b, as2, ad2, n);
    agg2_kernel<<<nb4, 256, 0, stream>>>(h2b, as2, ad2, b2, row_ptr, csr_src, outp, n);
}